// Round 5
// baseline (200.492 us; speedup 1.0000x reference)
//
#include <hip/hip_runtime.h>
#include <math.h>

#define DM   1024
#define TTOK 2048
#define NTOK 4096   // B*T

typedef __bf16 bf16x8 __attribute__((ext_vector_type(8)));
typedef __bf16 bf16x4 __attribute__((ext_vector_type(4)));
typedef float  f32x4  __attribute__((ext_vector_type(4)));

// Q pre-scale: sm_scale (1/8) * log2(e)  -> allows p = exp2(s)
#define QSCALE 0.18033688011112042f

#if defined(__has_builtin)
#if __has_builtin(__builtin_amdgcn_exp2f)
#define EXP2F(x) __builtin_amdgcn_exp2f(x)
#endif
#endif
#ifndef EXP2F
#define EXP2F(x) exp2f(x)
#endif

#define GLDS16(g, l) __builtin_amdgcn_global_load_lds( \
    (__attribute__((address_space(1))) void*)(g),      \
    (__attribute__((address_space(3))) void*)(l), 16, 0, 0)

// sum across the 4 quads (lanes ^16, ^32)
__device__ __forceinline__ float qsum(float v) {
    v += __shfl_xor(v, 16, 64);
    v += __shfl_xor(v, 32, 64);
    return v;
}

// ---------------- fp32 -> bf16 convert: x + 4 weights in ONE launch ----------------
__global__ __launch_bounds__(256)
void cvt_all(const float* __restrict__ x,  const float* __restrict__ Wq,
             const float* __restrict__ Wk, const float* __restrict__ Wv,
             const float* __restrict__ Wo, __bf16* __restrict__ dst) {
    size_t g = ((size_t)blockIdx.x * 256 + threadIdx.x) * 8;
    const float* s;
    size_t off;
    const size_t NX = (size_t)NTOK * DM;   // 4M
    if (g < NX) { s = x; off = g; }
    else {
        size_t gg = g - NX;
        int w = (int)(gg >> 20);           // 1M-element segments
        off = gg & ((1u << 20) - 1);
        s = (w == 0) ? Wq : (w == 1) ? Wk : (w == 2) ? Wv : Wo;
    }
    float4 a = *(const float4*)(s + off);
    float4 b = *(const float4*)(s + off + 4);
    bf16x8 v;
    v[0] = (__bf16)a.x; v[1] = (__bf16)a.y; v[2] = (__bf16)a.z; v[3] = (__bf16)a.w;
    v[4] = (__bf16)b.x; v[5] = (__bf16)b.y; v[6] = (__bf16)b.z; v[7] = (__bf16)b.w;
    *(bf16x8*)(dst + g) = v;
}

// =====================================================================
// bf16 MFMA GEMM: C[m,n] = sum_k A[m,k] * W[n,k]
// MODE 0: z=0 -> Q[b,h,t,d] scaled by QSCALE; z=1 -> K[b,h,t,d];
//         z=2 -> Vt[b,h,d,t] (packed b64 stores along t)
// MODE 1: fp32 row-major output (out-projection)
// =====================================================================
template<int MODE>
__global__ __launch_bounds__(256)
void gemm_bf16(const __bf16* __restrict__ A,
               const __bf16* __restrict__ W0, const __bf16* __restrict__ W1,
               const __bf16* __restrict__ W2,
               __bf16* __restrict__ Oq, __bf16* __restrict__ Ok,
               __bf16* __restrict__ Ovt, float* __restrict__ Of)
{
    const int z = (MODE == 0) ? blockIdx.z : 0;
    const __bf16* W = (z == 0) ? W0 : (z == 1) ? W1 : W2;

    __shared__ __attribute__((aligned(16))) __bf16 As[128 * 32];
    __shared__ __attribute__((aligned(16))) __bf16 Bs[128 * 32];

    const int tid  = threadIdx.x;
    const int lane = tid & 63;
    const int wave = tid >> 6;
    const int wm = wave & 1, wn = wave >> 1;
    const int col = lane & 15, quad = lane >> 4;
    const int m0 = blockIdx.y * 128, n0 = blockIdx.x * 128;

    const __bf16* Ag = A + (size_t)(m0 + (tid >> 2)) * DM + (tid & 3) * 8;
    const __bf16* Wg = W + (size_t)(n0 + (tid >> 2)) * DM + (tid & 3) * 8;
    __bf16* lA = As + tid * 8;
    __bf16* lB = Bs + tid * 8;

    f32x4 acc[4][4];
#pragma unroll
    for (int i = 0; i < 4; ++i)
#pragma unroll
        for (int j = 0; j < 4; ++j)
#pragma unroll
            for (int r = 0; r < 4; ++r) acc[i][j][r] = 0.0f;

    for (int k0 = 0; k0 < DM; k0 += 32) {
        __syncthreads();
        GLDS16(Ag + k0,                   lA);
        GLDS16(Ag + (size_t)64 * DM + k0, lA + 2048);
        GLDS16(Wg + k0,                   lB);
        GLDS16(Wg + (size_t)64 * DM + k0, lB + 2048);
        __syncthreads();
        bf16x8 af[4], bfr[4];
#pragma unroll
        for (int i = 0; i < 4; ++i)
            af[i] = *(const bf16x8*)&As[(wm * 64 + i * 16 + col) * 32 + quad * 8];
#pragma unroll
        for (int j = 0; j < 4; ++j)
            bfr[j] = *(const bf16x8*)&Bs[(wn * 64 + j * 16 + col) * 32 + quad * 8];
#pragma unroll
        for (int i = 0; i < 4; ++i)
#pragma unroll
            for (int j = 0; j < 4; ++j)
                acc[i][j] = __builtin_amdgcn_mfma_f32_16x16x32_bf16(af[i], bfr[j], acc[i][j], 0, 0, 0);
    }

#pragma unroll
    for (int i = 0; i < 4; ++i) {
#pragma unroll
        for (int j = 0; j < 4; ++j) {
            const int mb = m0 + wm * 64 + i * 16 + quad * 4;   // multiple of 4
            const int n  = n0 + wn * 64 + j * 16 + col;
            if (MODE == 1) {
#pragma unroll
                for (int r = 0; r < 4; ++r)
                    Of[(size_t)(mb + r) * DM + n] = acc[i][j][r];
            } else {
                const int b = mb >> 11, t = mb & 2047;
                const int h = n >> 6,  d = n & 63;
                if (z == 2) {
                    bf16x4 pk;
#pragma unroll
                    for (int r = 0; r < 4; ++r) pk[r] = (__bf16)acc[i][j][r];
                    *(bf16x4*)&Ovt[(((size_t)(b * 16 + h)) * 64 + d) * TTOK + t] = pk;
                } else {
                    __bf16* dst = ((z == 0) ? Oq : Ok) +
                                  ((((size_t)(b * 16 + h)) * TTOK + t) * 64 + d);
                    const float sc = (z == 0) ? QSCALE : 1.0f;
#pragma unroll
                    for (int r = 0; r < 4; ++r) dst[(size_t)r * 64] = (__bf16)(acc[i][j][r] * sc);
                }
            }
        }
    }
}

// =====================================================================
// MFMA flash attention v4: 512 threads (8 waves), 128 q/block, 16 q/wave.
// Register-prefetch pipeline: K/V for tile kb+1 loaded during compute of kb.
// S^T = K·Q^T ; p = exp2 (v_exp_f32, log2e folded into Q);
// l on matrix pipe: l = mfma(ones, P, l); O^T = V^T·P.
// Epilogue V snapshot from LDS at kb == own-q tile (no global gather).
// LDS 36 KB: Ks/Vs 9K + QPs 18K.
// =====================================================================
__global__ __launch_bounds__(512)
void attn_mfma(const __bf16* __restrict__ Qg, const __bf16* __restrict__ Kg,
               const __bf16* __restrict__ Vtg, __bf16* __restrict__ Zm)
{
    const int bh = blockIdx.y;
    const int q0 = blockIdx.x * 128;
    const size_t base = (size_t)bh * TTOK * 64;

    __shared__ __attribute__((aligned(16))) __bf16 Ks[64 * 72];
    __shared__ __attribute__((aligned(16))) __bf16 Vs[64 * 72];     // [d][key]
    __shared__ __attribute__((aligned(16))) __bf16 QPs[128 * 72];   // Q stage -> P [q][key]

    const int tid  = threadIdx.x;
    const int lane = tid & 63, wave = tid >> 6;   // wave 0..7
    const int col  = lane & 15, quad = lane >> 4;

    // ---- stage Q (pre-scaled by QSCALE in GEMM) ----
#pragma unroll
    for (int it = 0; it < 2; ++it) {
        int c = tid + 512 * it;
        int r = c >> 3, off = (c & 7) * 8;
        *(bf16x8*)&QPs[r * 72 + off] =
            *(const bf16x8*)(Qg + base + (size_t)(q0 + r) * 64 + off);
    }
    __syncthreads();
    bf16x8 qf[2];
#pragma unroll
    for (int ks = 0; ks < 2; ++ks)
        qf[ks] = *(const bf16x8*)&QPs[(wave * 16 + col) * 72 + ks * 32 + quad * 8];
    // wave w only overwrites rows [16w,16w+16) below = rows only it read -> no barrier

    bf16x8 ones;
#pragma unroll
    for (int i = 0; i < 8; ++i) ones[i] = (__bf16)1.0f;

    f32x4 O[4], lacc;
#pragma unroll
    for (int r = 0; r < 4; ++r) {
        lacc[r] = 0.0f;
#pragma unroll
        for (int nd = 0; nd < 4; ++nd) O[nd][r] = 0.0f;
    }

    const int rs = tid >> 3, offs = (tid & 7) * 8;   // 64 rows x 128 B staging

    // prefetch tile 0
    bf16x8 kreg = *(const bf16x8*)(Kg  + base + (size_t)rs * 64 + offs);
    bf16x8 vreg = *(const bf16x8*)(Vtg + base + (size_t)rs * TTOK + offs);

    // epilogue V snapshot coordinates: wave's q-rows live in key-tile kb_tgt
    const int kb_tgt = (q0 >> 6) + (wave >> 2);
    const int qo     = (wave & 3) * 16 + col;
    float vq[4][4];

    for (int kb = 0; kb < TTOK / 64; ++kb) {
        __syncthreads();   // prior tile's Ks/Vs frag reads complete
        *(bf16x8*)&Ks[rs * 72 + offs] = kreg;   // waits vmcnt here (after full compute phase)
        *(bf16x8*)&Vs[rs * 72 + offs] = vreg;
        __syncthreads();

        // issue next tile's loads NOW — latency spans the compute below
        {
            int kbn = (kb + 1) & (TTOK / 64 - 1);
            kreg = *(const bf16x8*)(Kg  + base + (size_t)(kbn * 64 + rs) * 64 + offs);
            vreg = *(const bf16x8*)(Vtg + base + (size_t)rs * TTOK + kbn * 64 + offs);
        }

        // ---- S^T = K · Q^T : rows = keys, cols = q(16) ----
        f32x4 s[4];
#pragma unroll
        for (int nk = 0; nk < 4; ++nk)
#pragma unroll
            for (int r = 0; r < 4; ++r) s[nk][r] = 0.0f;
#pragma unroll
        for (int ks = 0; ks < 2; ++ks) {
            bf16x8 kf[4];
#pragma unroll
            for (int nk = 0; nk < 4; ++nk)
                kf[nk] = *(const bf16x8*)&Ks[(nk * 16 + col) * 72 + ks * 32 + quad * 8];
#pragma unroll
            for (int nk = 0; nk < 4; ++nk)
                s[nk] = __builtin_amdgcn_mfma_f32_16x16x32_bf16(kf[nk], qf[ks], s[nk], 0, 0, 0);
        }

        // ---- p = exp2(s); write P[q][key] (b64) ----
#pragma unroll
        for (int nk = 0; nk < 4; ++nk) {
            float p0 = EXP2F(s[nk][0]);
            float p1 = EXP2F(s[nk][1]);
            float p2 = EXP2F(s[nk][2]);
            float p3 = EXP2F(s[nk][3]);
            bf16x4 pk;
            pk[0] = (__bf16)p0; pk[1] = (__bf16)p1;
            pk[2] = (__bf16)p2; pk[3] = (__bf16)p3;
            *(bf16x4*)&QPs[(wave * 16 + col) * 72 + nk * 16 + quad * 4] = pk;
        }

        // ---- O^T += V^T · P ; l += 1 · P  (all intra-wave) ----
#pragma unroll
        for (int ks = 0; ks < 2; ++ks) {
            bf16x8 pf = *(const bf16x8*)&QPs[(wave * 16 + col) * 72 + ks * 32 + quad * 8];
            lacc = __builtin_amdgcn_mfma_f32_16x16x32_bf16(ones, pf, lacc, 0, 0, 0);
#pragma unroll
            for (int nd = 0; nd < 4; ++nd) {
                bf16x8 vf = *(const bf16x8*)&Vs[(nd * 16 + col) * 72 + ks * 32 + quad * 8];
                O[nd] = __builtin_amdgcn_mfma_f32_16x16x32_bf16(vf, pf, O[nd], 0, 0, 0);
            }
        }

        // ---- snapshot own-q V columns from LDS (wave-uniform branch) ----
        if (kb == kb_tgt) {
#pragma unroll
            for (int nd = 0; nd < 4; ++nd)
#pragma unroll
                for (int r = 0; r < 4; ++r)
                    vq[nd][r] = (float)Vs[(nd * 16 + quad * 4 + r) * 72 + qo];
        }
    }

    // every lane holds l[q=col] in each lacc component
    const float inv = 1.0f / lacc[0];

    // ---- epilogue: Y = O/l ; exclusive output mod ; packed bf16 store ----
    const int b = bh >> 4, h = bh & 15;
    const int q = q0 + wave * 16 + col;
    float y[4][4];
    float yv = 0.f, v2 = 0.f, yy = 0.f;
#pragma unroll
    for (int nd = 0; nd < 4; ++nd)
#pragma unroll
        for (int r = 0; r < 4; ++r) {
            float yval = O[nd][r] * inv;
            float vval = vq[nd][r];
            y[nd][r] = yval;
            yv += yval * vval; v2 += vval * vval; yy += yval * yval;
        }
    yv = qsum(yv); v2 = qsum(v2); yy = qsum(yy);
    float scl = (v2 > 0.0f) ? yv / fmaxf(v2, 1.1754943508222875e-38f) : 0.0f;
    float zz = 0.f;
    float zv[4][4];
#pragma unroll
    for (int nd = 0; nd < 4; ++nd)
#pragma unroll
        for (int r = 0; r < 4; ++r) {
            zv[nd][r] = y[nd][r] - scl * vq[nd][r];
            zz += zv[nd][r] * zv[nd][r];
        }
    zz = qsum(zz);
    float znorm = sqrtf(zz);
    float refn  = fmaxf(sqrtf(yy), sqrtf(v2));
    bool  wipe  = (v2 > 0.0f) && (znorm <= 1.1920928955078125e-07f * 64.0f * refn);
#pragma unroll
    for (int nd = 0; nd < 4; ++nd) {
        bf16x4 pk;
#pragma unroll
        for (int r = 0; r < 4; ++r) pk[r] = (__bf16)(wipe ? 0.0f : zv[nd][r]);
        *(bf16x4*)&Zm[((size_t)(b * TTOK + q)) * DM + h * 64 + nd * 16 + quad * 4] = pk;
    }
}

// =====================================================================
extern "C" void kernel_launch(void* const* d_in, const int* in_sizes, int n_in,
                              void* d_out, int out_size, void* d_ws, size_t ws_size,
                              hipStream_t stream) {
    const float* x  = (const float*)d_in[0];
    const float* Wq = (const float*)d_in[1];
    const float* Wk = (const float*)d_in[2];
    const float* Wv = (const float*)d_in[3];
    const float* Wo = (const float*)d_in[4];

    const size_t NX = (size_t)NTOK * DM;   // 4M
    const size_t NW = (size_t)DM * DM;     // 1M
    __bf16* xb  = (__bf16*)d_ws;
    __bf16* wqb = xb  + NX;
    __bf16* wkb = wqb + NW;
    __bf16* wvb = wkb + NW;
    __bf16* wob = wvb + NW;
    __bf16* Qb  = wob + NW;
    __bf16* Kb  = Qb  + NX;
    __bf16* Vtb = Kb  + NX;
    __bf16* Zmb = Vtb + NX;   // total 24M bf16 = 48 MB

    cvt_all<<<(NX + 4 * NW) / 2048, 256, 0, stream>>>(x, Wq, Wk, Wv, Wo, xb);

    gemm_bf16<0><<<dim3(DM / 128, NTOK / 128, 3), 256, 0, stream>>>(
        xb, wqb, wkb, wvb, Qb, Kb, Vtb, nullptr);

    attn_mfma<<<dim3(TTOK / 128, 32), 512, 0, stream>>>(Qb, Kb, Vtb, Zmb);

    gemm_bf16<1><<<dim3(DM / 128, NTOK / 128, 1), 256, 0, stream>>>(
        Zmb, wob, wob, wob, nullptr, nullptr, nullptr, (float*)d_out);
}